// Round 9
// baseline (9225.499 us; speedup 1.0000x reference)
//
#include <hip/hip_runtime.h>

#define NB 16384
#define NT 1024

typedef _Float16 h8 __attribute__((ext_vector_type(8)));
typedef float    f4 __attribute__((ext_vector_type(4)));

// AS4 scalar loads for wave-uniform data (ts).
typedef __attribute__((address_space(4))) const float cfloat;
static __device__ __forceinline__ const cfloat* as_const(const float* p) {
  return (const cfloat*)(unsigned long long)p;
}

// tanh(x) = 1 - 2/(exp(2x)+1); ~2-3e-7 abs error; correct saturation at +/-inf.
static __device__ __forceinline__ float tanh_fast(float x) {
  float e = __builtin_amdgcn_exp2f(x * 2.88539008177792681f);
  return fmaf(-2.0f, __builtin_amdgcn_rcpf(e + 1.0f), 1.0f);
}

// 2-term f16 split: x = hi + lo, error ~2^-22 relative (fp32-grade across K=64).
static __device__ __forceinline__ void split_f16(float x, _Float16& hi, _Float16& lo) {
  hi = (_Float16)x;
  lo = (_Float16)(x - (float)hi);
}

union H8U { unsigned u[4]; h8 v; };

// Pin into VGPR (generous register budget required: min_waves=1 -> VGPR 108,
// allocator keeps the persistent set; tight bounds (r7: (1024,4)) snap to 64
// VGPR and rematerialize W2 loads in-loop -> 34.8 GB FETCH catastrophe).
#define PINV(x) asm volatile("" : "+v"(x))

static __device__ __forceinline__ h8 mkh8(const unsigned* u) {
  H8U t; t.u[0] = u[0]; t.u[1] = u[1]; t.u[2] = u[2]; t.u[3] = u[3]; return t.v;
}

// ---- Round 9: issue-saturation on ALL SIMDs ----
// Calibrated model (r6 + r8): per wave-eval issue I ~= 1790 cyc (57% trans pipe:
// 64 trans-inst x 16 cyc), hideable latency L ~= 240. A SIMD saturates at 2
// waves; r8's error was halving SIMD count to get them. Here: 2048 waves x
// 8 REAL cols each (cols duplicated across the unused half of the MFMA n-dim
// via col&7 — per-wave instruction count unchanged, every lane computes valid
// data, stores guarded to the first copy). 256 blocks x 512 threads ->
// 1 block/CU, 8 waves/CU = 2/SIMD on all 256 CUs. Wall = 6138 x I ~= 4.6 ms.
__global__ __launch_bounds__(512, 1)
void node_step_kernel(const float* __restrict__ y0,
                      const float* __restrict__ ts,
                      const float* __restrict__ W1,
                      const float* __restrict__ b1,
                      const float* __restrict__ W2,
                      const float* __restrict__ b2,
                      const float* __restrict__ W3,
                      const float* __restrict__ b3,
                      float* __restrict__ out)
{
  const int lane = (int)(threadIdx.x & 63);
  const int wv   = (int)(threadIdx.x >> 6);   // 0..7
  const int col  = lane & 15;                 // MFMA n-slot (0..15)
  const int quad = lane >> 4;
  // 8 real columns per wave; n-slots 8..15 duplicate 0..7 (valid data, not stored).
  const int gb   = (int)blockIdx.x * 64 + wv * 8 + (col & 7);

  // ---- init: W2 A-fragments (full m=64), hi/lo f16, pinned ----
  // A-frag (HW-verified r5/r6): A[m = lane&15][k = quad*8 + j]; k-step adds 32.
  unsigned afh[4][2][4], afl[4][2][4];        // [mtile][kstep][dword]
#pragma unroll
  for (int mt = 0; mt < 4; ++mt) {
    const int m = mt * 16 + col;
#pragma unroll
    for (int ks = 0; ks < 2; ++ks) {
      const float* wp = W2 + m * 64 + ks * 32 + quad * 8;
      H8U hu, lu;
#pragma unroll
      for (int i = 0; i < 8; ++i) {
        _Float16 a, b; split_f16(wp[i], a, b);
        hu.v[i] = a; lu.v[i] = b;
      }
#pragma unroll
      for (int i = 0; i < 4; ++i) {
        afh[mt][ks][i] = hu.u[i];  PINV(afh[mt][ks][i]);
        afl[mt][ks][i] = lu.u[i];  PINV(afl[mt][ks][i]);
      }
    }
  }

  // b2 (acc init) and W3 rows in C/D layout (HW-verified: col = lane&15,
  // row = mt*16 + quad*4 + reg). Pinned.
  float accb[4][4], w30[4][4], w31[4][4];
#pragma unroll
  for (int mt = 0; mt < 4; ++mt) {
#pragma unroll
    for (int r = 0; r < 4; ++r) {
      const int j2 = mt * 16 + quad * 4 + r;
      accb[mt][r] = b2[j2];      PINV(accb[mt][r]);
      w30[mt][r]  = W3[j2];      PINV(w30[mt][r]);
      w31[mt][r]  = W3[64 + j2]; PINV(w31[mt][r]);
    }
  }

  // L1 weights for exactly the 16 rows this lane's B-fragments cover.
  float w1a[16], w1b[16], b1r[16];
#pragma unroll
  for (int i = 0; i < 16; ++i) {
    const int row = (i < 8) ? (quad * 8 + i) : (32 + quad * 8 + (i - 8));
    w1a[i] = W1[2 * row];     PINV(w1a[i]);
    w1b[i] = W1[2 * row + 1]; PINV(w1b[i]);
    b1r[i] = b1[row];         PINV(b1r[i]);
  }
  const cfloat* tsc = as_const(ts);
  const float b30 = b3[0], b31 = b3[1];

  float yx = y0[2 * gb], yy = y0[2 * gb + 1];

  float2* __restrict__ outv = (float2*)out;
  const bool writer = (quad == 0) && (col < 8);
  if (writer) outv[gb] = make_float2(yx, yy);   // SaveAt includes t0

  const float A21 = (float)(1.0/5.0);
  const float A31 = (float)(3.0/40.0),  A32 = (float)(9.0/40.0);
  const float A41 = (float)(44.0/45.0), A42 = (float)(-56.0/15.0), A43 = (float)(32.0/9.0);
  const float A51 = (float)(19372.0/6561.0), A52 = (float)(-25360.0/2187.0),
              A53 = (float)(64448.0/6561.0), A54 = (float)(-212.0/729.0);
  const float A61 = (float)(9017.0/3168.0), A62 = (float)(-355.0/33.0),
              A63 = (float)(46732.0/5247.0), A64 = (float)(49.0/176.0),
              A65 = (float)(-5103.0/18656.0);
  const float BB1 = (float)(35.0/384.0), BB3 = (float)(500.0/1113.0),
              BB4 = (float)(125.0/192.0), BB5 = (float)(-2187.0/6784.0),
              BB6 = (float)(11.0/84.0);

  float k1x,k1y,k2x,k2y,k3x,k3y,k4x,k4y,k5x,k5y,k6x,k6y;

  for (int t = 0; t < NT - 1; ++t) {
    const float dt = tsc[t + 1] - tsc[t];

    auto EVAL = [&](float ysx, float ysy, float& kx, float& ky) {
      // ---- L1: 16 h1 rows for my column, straight into B-fragments ----
      h8 bh0, bh1, bl0, bl1;
#pragma unroll
      for (int i = 0; i < 16; ++i) {
        const float hv = tanh_fast(fmaf(w1a[i], ysx, fmaf(w1b[i], ysy, b1r[i])));
        _Float16 a, b; split_f16(hv, a, b);
        if (i < 8) { bh0[i] = a;     bl0[i] = b; }
        else       { bh1[i - 8] = a; bl1[i - 8] = b; }
      }

      // ---- L2: 4 m-tiles x (2 k-steps x 3 split products) MFMA ----
      float p0 = 0.0f, p1 = 0.0f;
#pragma unroll
      for (int mt = 0; mt < 4; ++mt) {
        const h8 ah0 = mkh8(afh[mt][0]), al0 = mkh8(afl[mt][0]);
        const h8 ah1 = mkh8(afh[mt][1]), al1 = mkh8(afl[mt][1]);
        f4 c = { accb[mt][0], accb[mt][1], accb[mt][2], accb[mt][3] };
        c = __builtin_amdgcn_mfma_f32_16x16x32_f16(al0, bh0, c, 0, 0, 0);
        c = __builtin_amdgcn_mfma_f32_16x16x32_f16(ah0, bl0, c, 0, 0, 0);
        c = __builtin_amdgcn_mfma_f32_16x16x32_f16(ah0, bh0, c, 0, 0, 0);
        c = __builtin_amdgcn_mfma_f32_16x16x32_f16(al1, bh1, c, 0, 0, 0);
        c = __builtin_amdgcn_mfma_f32_16x16x32_f16(ah1, bl1, c, 0, 0, 0);
        c = __builtin_amdgcn_mfma_f32_16x16x32_f16(ah1, bh1, c, 0, 0, 0);
        // ---- L3 partials: tanh + W3, rows mt*16+quad*4+r of my column ----
#pragma unroll
        for (int r = 0; r < 4; ++r) {
          const float h2 = tanh_fast(c[r]);
          p0 = fmaf(w30[mt][r], h2, p0);
          p1 = fmaf(w31[mt][r], h2, p1);
        }
      }
      // quad butterfly: lanes col, col^16, col^32, col^48 hold the 4 row-quarters
      p0 += __shfl_xor(p0, 16); p1 += __shfl_xor(p1, 16);
      p0 += __shfl_xor(p0, 32); p1 += __shfl_xor(p1, 32);
      kx = p0 + b30;
      ky = p1 + b31;
    };

    EVAL(yx, yy, k1x, k1y);
    EVAL(fmaf(dt, A21 * k1x, yx), fmaf(dt, A21 * k1y, yy), k2x, k2y);
    {
      float cx = fmaf(A32, k2x, A31 * k1x);
      float cy = fmaf(A32, k2y, A31 * k1y);
      EVAL(fmaf(dt, cx, yx), fmaf(dt, cy, yy), k3x, k3y);
    }
    {
      float cx = fmaf(A43, k3x, fmaf(A42, k2x, A41 * k1x));
      float cy = fmaf(A43, k3y, fmaf(A42, k2y, A41 * k1y));
      EVAL(fmaf(dt, cx, yx), fmaf(dt, cy, yy), k4x, k4y);
    }
    {
      float cx = fmaf(A54, k4x, fmaf(A53, k3x, fmaf(A52, k2x, A51 * k1x)));
      float cy = fmaf(A54, k4y, fmaf(A53, k3y, fmaf(A52, k2y, A51 * k1y)));
      EVAL(fmaf(dt, cx, yx), fmaf(dt, cy, yy), k5x, k5y);
    }
    {
      float cx = fmaf(A65, k5x, fmaf(A64, k4x, fmaf(A63, k3x, fmaf(A62, k2x, A61 * k1x))));
      float cy = fmaf(A65, k5y, fmaf(A64, k4y, fmaf(A63, k3y, fmaf(A62, k2y, A61 * k1y))));
      EVAL(fmaf(dt, cx, yx), fmaf(dt, cy, yy), k6x, k6y);
    }
    {
      float cx = fmaf(BB6, k6x, fmaf(BB5, k5x, fmaf(BB4, k4x, fmaf(BB3, k3x, BB1 * k1x))));
      float cy = fmaf(BB6, k6y, fmaf(BB5, k5y, fmaf(BB4, k4y, fmaf(BB3, k3y, BB1 * k1y))));
      yx = fmaf(dt, cx, yx);
      yy = fmaf(dt, cy, yy);
    }
    if (writer) outv[(t + 1) * NB + gb] = make_float2(yx, yy);
  }
}

extern "C" void kernel_launch(void* const* d_in, const int* in_sizes, int n_in,
                              void* d_out, int out_size, void* d_ws, size_t ws_size,
                              hipStream_t stream) {
  const float* y0 = (const float*)d_in[0];
  const float* ts = (const float*)d_in[1];
  const float* W1 = (const float*)d_in[2];
  const float* b1 = (const float*)d_in[3];
  const float* W2 = (const float*)d_in[4];
  const float* b2 = (const float*)d_in[5];
  const float* W3 = (const float*)d_in[6];
  const float* b3 = (const float*)d_in[7];
  float* out = (float*)d_out;

  // 256 blocks x 512 threads = 2048 waves (8 real cols each):
  // 1 block/CU, 8 waves/CU = 2 waves/SIMD on all 256 CUs.
  node_step_kernel<<<dim3(NB / 64), dim3(512), 0, stream>>>(
      y0, ts, W1, b1, W2, b2, W3, b3, out);
}

// Round 11
// 4799.287 us; speedup vs baseline: 1.9223x; 1.9223x over previous
//
#include <hip/hip_runtime.h>

#define NB 16384
#define NT 1024

typedef _Float16 h8  __attribute__((ext_vector_type(8)));
typedef __fp16   g2  __attribute__((ext_vector_type(2)));   // cvt_pkrtz result type
typedef float    f4  __attribute__((ext_vector_type(4)));

// AS4 scalar loads for wave-uniform data (ts).
typedef __attribute__((address_space(4))) const float cfloat;
static __device__ __forceinline__ const cfloat* as_const(const float* p) {
  return (const cfloat*)(unsigned long long)p;
}

// Pre-scaled tanh: input already multiplied by 2*log2(e) (folded into weights).
// tanh(x) = 1 - 2/(exp2(xs)+1), xs = 2*log2(e)*x. 4 inst: exp, add, rcp, fma.
static __device__ __forceinline__ float tanh_ps(float xs) {
  float e = __builtin_amdgcn_exp2f(xs);
  return fmaf(-2.0f, __builtin_amdgcn_rcpf(e + 1.0f), 1.0f);
}

#define TANH_SCALE 2.88539008177792681f  // 2*log2(e)

union H8U { h8 v; g2 p[4]; };  // type-pun: 4 packed pairs <-> one MFMA operand

// Pin into VGPR (generous budget required: min_waves=1; r7 proved tight bounds
// re-trigger in-loop rematerialization of the W2 loads -> 34.8 GB FETCH).
#define PINV(x)  asm volatile("" : "+v"(x))

// ---- Round 11 = round 10 with the cvt_pkrtz type fixed ----
// r6 geometry (proven optimal: 16 real cols/wave, 1 wave/SIMD, full chip) +
// issue-count surgery. Calibrated model: I ~= 1840 cyc/wave-eval, L ~= 450;
// 2 waves/SIMD = exactly 2I (r8/r9) so TLP cannot help; only I can shrink.
// Trims: (1) A-fragments live as pinned h8 values -> no operand-staging movs;
// (2) 2*log2(e) folded into W1/b1/W2/b2 -> tanh is 4 inst (saves 32 muls/eval);
// (3) v_cvt_pkrtz pair-packing for the f16 hi/lo split.
__global__ __launch_bounds__(256, 1)
void node_step_kernel(const float* __restrict__ y0,
                      const float* __restrict__ ts,
                      const float* __restrict__ W1,
                      const float* __restrict__ b1,
                      const float* __restrict__ W2,
                      const float* __restrict__ b2,
                      const float* __restrict__ W3,
                      const float* __restrict__ b3,
                      float* __restrict__ out)
{
  const int lane = (int)(threadIdx.x & 63);
  const int wv   = (int)(threadIdx.x >> 6);   // 0..3
  const int col  = lane & 15;                 // batch column within wave
  const int quad = lane >> 4;
  const int gb   = (int)blockIdx.x * 64 + wv * 16 + col;

  // ---- init: W2 A-fragments (x TANH_SCALE), hi/lo f16, as pinned h8 ----
  // A-frag (HW-verified r5/r6): A[m = lane&15][k = quad*8 + j]; k-step adds 32.
  h8 Ah[4][2], Al[4][2];                      // [mtile][kstep]
#pragma unroll
  for (int mt = 0; mt < 4; ++mt) {
    const int m = mt * 16 + col;
#pragma unroll
    for (int ks = 0; ks < 2; ++ks) {
      const float* wp = W2 + m * 64 + ks * 32 + quad * 8;
      H8U hu, lu;
#pragma unroll
      for (int p = 0; p < 4; ++p) {
        const float x0 = wp[2*p]     * TANH_SCALE;
        const float x1 = wp[2*p + 1] * TANH_SCALE;
        const g2 hi = __builtin_amdgcn_cvt_pkrtz(x0, x1);
        hu.p[p] = hi;
        lu.p[p] = __builtin_amdgcn_cvt_pkrtz(x0 - (float)hi.x, x1 - (float)hi.y);
      }
      Ah[mt][ks] = hu.v;  PINV(Ah[mt][ks]);
      Al[mt][ks] = lu.v;  PINV(Al[mt][ks]);
    }
  }

  // b2 (x TANH_SCALE, acc init) and W3 rows in C/D layout (HW-verified:
  // col = lane&15, row = mt*16 + quad*4 + reg). Pinned.
  float accb[4][4], w30[4][4], w31[4][4];
#pragma unroll
  for (int mt = 0; mt < 4; ++mt) {
#pragma unroll
    for (int r = 0; r < 4; ++r) {
      const int j2 = mt * 16 + quad * 4 + r;
      accb[mt][r] = b2[j2] * TANH_SCALE;  PINV(accb[mt][r]);
      w30[mt][r]  = W3[j2];               PINV(w30[mt][r]);
      w31[mt][r]  = W3[64 + j2];          PINV(w31[mt][r]);
    }
  }

  // L1 weights (x TANH_SCALE) for exactly the 16 rows this lane's B-fragments
  // cover: i<8 -> row = quad*8+i (kstep0); i>=8 -> row = 32+quad*8+(i-8).
  float w1a[16], w1b[16], b1r[16];
#pragma unroll
  for (int i = 0; i < 16; ++i) {
    const int row = (i < 8) ? (quad * 8 + i) : (32 + quad * 8 + (i - 8));
    w1a[i] = W1[2 * row]     * TANH_SCALE;  PINV(w1a[i]);
    w1b[i] = W1[2 * row + 1] * TANH_SCALE;  PINV(w1b[i]);
    b1r[i] = b1[row]         * TANH_SCALE;  PINV(b1r[i]);
  }
  const cfloat* tsc = as_const(ts);
  const float b30 = b3[0], b31 = b3[1];

  float yx = y0[2 * gb], yy = y0[2 * gb + 1];

  float2* __restrict__ outv = (float2*)out;
  if (quad == 0) outv[gb] = make_float2(yx, yy);   // SaveAt includes t0

  const float A21 = (float)(1.0/5.0);
  const float A31 = (float)(3.0/40.0),  A32 = (float)(9.0/40.0);
  const float A41 = (float)(44.0/45.0), A42 = (float)(-56.0/15.0), A43 = (float)(32.0/9.0);
  const float A51 = (float)(19372.0/6561.0), A52 = (float)(-25360.0/2187.0),
              A53 = (float)(64448.0/6561.0), A54 = (float)(-212.0/729.0);
  const float A61 = (float)(9017.0/3168.0), A62 = (float)(-355.0/33.0),
              A63 = (float)(46732.0/5247.0), A64 = (float)(49.0/176.0),
              A65 = (float)(-5103.0/18656.0);
  const float BB1 = (float)(35.0/384.0), BB3 = (float)(500.0/1113.0),
              BB4 = (float)(125.0/192.0), BB5 = (float)(-2187.0/6784.0),
              BB6 = (float)(11.0/84.0);

  float k1x,k1y,k2x,k2y,k3x,k3y,k4x,k4y,k5x,k5y,k6x,k6y;

  for (int t = 0; t < NT - 1; ++t) {
    const float dt = tsc[t + 1] - tsc[t];

    auto EVAL = [&](float ysx, float ysy, float& kx, float& ky) {
      // ---- L1: 16 h1 rows (pre-scaled weights -> 2 fma + 4-inst tanh) ----
      float hv[16];
#pragma unroll
      for (int i = 0; i < 16; ++i)
        hv[i] = tanh_ps(fmaf(w1a[i], ysx, fmaf(w1b[i], ysy, b1r[i])));

      // pair-pack into B-fragments via v_cvt_pkrtz (hi) + residual pack (lo)
      H8U BH0, BL0, BH1, BL1;
#pragma unroll
      for (int p = 0; p < 4; ++p) {
        const g2 h0 = __builtin_amdgcn_cvt_pkrtz(hv[2*p], hv[2*p+1]);
        BH0.p[p] = h0;
        BL0.p[p] = __builtin_amdgcn_cvt_pkrtz(hv[2*p]   - (float)h0.x,
                                              hv[2*p+1] - (float)h0.y);
        const g2 h1 = __builtin_amdgcn_cvt_pkrtz(hv[8+2*p], hv[9+2*p]);
        BH1.p[p] = h1;
        BL1.p[p] = __builtin_amdgcn_cvt_pkrtz(hv[8+2*p] - (float)h1.x,
                                              hv[9+2*p] - (float)h1.y);
      }

      // ---- L2: 4 m-tiles x (2 k-steps x 3 split products) MFMA ----
      float p0 = 0.0f, p1 = 0.0f;
#pragma unroll
      for (int mt = 0; mt < 4; ++mt) {
        f4 c = { accb[mt][0], accb[mt][1], accb[mt][2], accb[mt][3] };
        c = __builtin_amdgcn_mfma_f32_16x16x32_f16(Al[mt][0], BH0.v, c, 0, 0, 0);
        c = __builtin_amdgcn_mfma_f32_16x16x32_f16(Ah[mt][0], BL0.v, c, 0, 0, 0);
        c = __builtin_amdgcn_mfma_f32_16x16x32_f16(Ah[mt][0], BH0.v, c, 0, 0, 0);
        c = __builtin_amdgcn_mfma_f32_16x16x32_f16(Al[mt][1], BH1.v, c, 0, 0, 0);
        c = __builtin_amdgcn_mfma_f32_16x16x32_f16(Ah[mt][1], BL1.v, c, 0, 0, 0);
        c = __builtin_amdgcn_mfma_f32_16x16x32_f16(Ah[mt][1], BH1.v, c, 0, 0, 0);
        // ---- L3 partials: tanh (pre-scale folded into W2/b2) + W3 ----
#pragma unroll
        for (int r = 0; r < 4; ++r) {
          const float h2 = tanh_ps(c[r]);
          p0 = fmaf(w30[mt][r], h2, p0);
          p1 = fmaf(w31[mt][r], h2, p1);
        }
      }
      // quad butterfly: lanes col, col^16, col^32, col^48 hold the 4 row-quarters
      p0 += __shfl_xor(p0, 16); p1 += __shfl_xor(p1, 16);
      p0 += __shfl_xor(p0, 32); p1 += __shfl_xor(p1, 32);
      kx = p0 + b30;
      ky = p1 + b31;
    };

    EVAL(yx, yy, k1x, k1y);
    EVAL(fmaf(dt, A21 * k1x, yx), fmaf(dt, A21 * k1y, yy), k2x, k2y);
    {
      float cx = fmaf(A32, k2x, A31 * k1x);
      float cy = fmaf(A32, k2y, A31 * k1y);
      EVAL(fmaf(dt, cx, yx), fmaf(dt, cy, yy), k3x, k3y);
    }
    {
      float cx = fmaf(A43, k3x, fmaf(A42, k2x, A41 * k1x));
      float cy = fmaf(A43, k3y, fmaf(A42, k2y, A41 * k1y));
      EVAL(fmaf(dt, cx, yx), fmaf(dt, cy, yy), k4x, k4y);
    }
    {
      float cx = fmaf(A54, k4x, fmaf(A53, k3x, fmaf(A52, k2x, A51 * k1x)));
      float cy = fmaf(A54, k4y, fmaf(A53, k3y, fmaf(A52, k2y, A51 * k1y)));
      EVAL(fmaf(dt, cx, yx), fmaf(dt, cy, yy), k5x, k5y);
    }
    {
      float cx = fmaf(A65, k5x, fmaf(A64, k4x, fmaf(A63, k3x, fmaf(A62, k2x, A61 * k1x))));
      float cy = fmaf(A65, k5y, fmaf(A64, k4y, fmaf(A63, k3y, fmaf(A62, k2y, A61 * k1y))));
      EVAL(fmaf(dt, cx, yx), fmaf(dt, cy, yy), k6x, k6y);
    }
    {
      float cx = fmaf(BB6, k6x, fmaf(BB5, k5x, fmaf(BB4, k4x, fmaf(BB3, k3x, BB1 * k1x))));
      float cy = fmaf(BB6, k6y, fmaf(BB5, k5y, fmaf(BB4, k4y, fmaf(BB3, k3y, BB1 * k1y))));
      yx = fmaf(dt, cx, yx);
      yy = fmaf(dt, cy, yy);
    }
    if (quad == 0) outv[(t + 1) * NB + gb] = make_float2(yx, yy);
  }
}

extern "C" void kernel_launch(void* const* d_in, const int* in_sizes, int n_in,
                              void* d_out, int out_size, void* d_ws, size_t ws_size,
                              hipStream_t stream) {
  const float* y0 = (const float*)d_in[0];
  const float* ts = (const float*)d_in[1];
  const float* W1 = (const float*)d_in[2];
  const float* b1 = (const float*)d_in[3];
  const float* W2 = (const float*)d_in[4];
  const float* b2 = (const float*)d_in[5];
  const float* W3 = (const float*)d_in[6];
  const float* b3 = (const float*)d_in[7];
  float* out = (float*)d_out;

  // 256 blocks x 256 threads = 1024 waves (16 real cols each):
  // 1 wave/SIMD on all 256 CUs — proven-optimal geometry (r6 vs r8/r9).
  node_step_kernel<<<dim3(NB / 64), dim3(256), 0, stream>>>(
      y0, ts, W1, b1, W2, b2, W3, b3, out);
}